// Round 11
// baseline (1422.241 us; speedup 1.0000x reference)
//
#include <hip/hip_runtime.h>
#include <hip/hip_bf16.h>

typedef unsigned short ushort_t;
typedef unsigned int uint_t;

#define S_LEN 4096
#define BATCH 4
#define DMODEL 1040
#define KPAD 1056          // 1040 padded to 33*32 (hs K)
#define KO 1152            // attn feature dim: 16 heads * 72; O-GEMM K
#define NPADW 1152
#define M_H 8192           // rows per half (2 batches)
#define KVSPLIT 32         // kv-state split count

using f32x4 = __attribute__((ext_vector_type(4))) float;
using bf16x8 = __attribute__((ext_vector_type(8))) __bf16;
using f16x8 = __attribute__((ext_vector_type(8))) _Float16;

// fp16 two-plane split, lo plane pre-scaled by 2^12
__device__ __forceinline__ void splitf16(float x, ushort_t& h, ushort_t& l) {
  _Float16 hf = (_Float16)x;
  float r = (x - (float)hf) * 4096.0f;
  _Float16 lf = (_Float16)r;
  h = __builtin_bit_cast(ushort_t, hf);
  l = __builtin_bit_cast(ushort_t, lf);
}

typedef const __attribute__((address_space(1))) unsigned int* gas_u32p;
typedef __attribute__((address_space(3))) unsigned int* las_u32p;
__device__ __forceinline__ void gload_lds16(const ushort_t* g, ushort_t* l) {
  __builtin_amdgcn_global_load_lds((gas_u32p)g, (las_u32p)l, 16, 0, 0);
}

// XCD-chunked tile map: XCD x owns m-panels [x*8, x*8+8), n-inner order.
__device__ __forceinline__ void tile_map(int lid, int NT, int& m0, int& n0) {
  const int x = lid & 7, pos = lid >> 3;
  const int mi = pos / NT, ni = pos - mi * NT;
  m0 = (x * 8 + mi) * 128;
  n0 = ni * 128;
}

union pack8 { ushort_t u[8]; uint4 v; };

// ---------------- split hs rows [M_H][1040] f32 -> fp16 h/l' planes [M_H][KPAD] -------
__global__ __launch_bounds__(256) void split_hs_kernel(const float* __restrict__ hs,
                                                       ushort_t* __restrict__ hh,
                                                       ushort_t* __restrict__ hl) {
  const int C8 = KPAD / 8;  // 132
  int idx = blockIdx.x * 256 + threadIdx.x;
  if (idx >= M_H * C8) return;
  int row = idx / C8, col = (idx % C8) * 8;
  pack8 ph, pl;
  if (col < DMODEL) {
    const float* p = &hs[(size_t)row * DMODEL + col];
#pragma unroll
    for (int j = 0; j < 8; ++j) splitf16(p[j], ph.u[j], pl.u[j]);
  } else {
#pragma unroll
    for (int j = 0; j < 8; ++j) { ph.u[j] = 0; pl.u[j] = 0; }
  }
  size_t o = (size_t)row * KPAD + col;
  *reinterpret_cast<uint4*>(&hh[o]) = ph.v;
  *reinterpret_cast<uint4*>(&hl[o]) = pl.v;
}

// ------- Wq||Wk transpose+split (fp16 scaled): Wt[n<1024][k<1056] ---------------------
__global__ __launch_bounds__(256) void split_wqk_kernel(const float* __restrict__ Wq,
                                                        const float* __restrict__ Wk,
                                                        ushort_t* __restrict__ th,
                                                        ushort_t* __restrict__ tl) {
  const int C8 = KPAD / 8;
  int idx = blockIdx.x * 256 + threadIdx.x;
  if (idx >= 1024 * C8) return;
  int n = idx / C8, k = (idx % C8) * 8;
  pack8 ph, pl;
#pragma unroll
  for (int j = 0; j < 8; ++j) {
    int kk = k + j;
    float val = 0.f;
    if (kk < DMODEL) val = (n < 512) ? Wq[(size_t)kk * 512 + n] : Wk[(size_t)kk * 512 + (n - 512)];
    splitf16(val, ph.u[j], pl.u[j]);
  }
  size_t o = (size_t)n * KPAD + k;
  *reinterpret_cast<uint4*>(&th[o]) = ph.v;
  *reinterpret_cast<uint4*>(&tl[o]) = pl.v;
}

// ------- Wv transpose (fp16 hi only): Wt[n<1152][k<1056] ------------------------------
__global__ __launch_bounds__(256) void split_wv_kernel(const float* __restrict__ Wv,
                                                       ushort_t* __restrict__ th) {
  const int C8 = KPAD / 8;
  int idx = blockIdx.x * 256 + threadIdx.x;
  if (idx >= NPADW * C8) return;
  int n = idx / C8, k = (idx % C8) * 8;
  pack8 ph;
#pragma unroll
  for (int j = 0; j < 8; ++j) {
    int kk = k + j;
    float val = (n < DMODEL && kk < DMODEL) ? Wv[(size_t)kk * DMODEL + n] : 0.f;
    ph.u[j] = __builtin_bit_cast(ushort_t, (_Float16)val);
  }
  *reinterpret_cast<uint4*>(&th[(size_t)n * KPAD + k]) = ph.v;
}

// ------- Wo transpose (bf16 single plane) with attn k-mapping k' = h*72+e -------------
__global__ __launch_bounds__(256) void split_wo_kernel(const float* __restrict__ Wo,
                                                       ushort_t* __restrict__ th) {
  const int C8O = KO / 8;  // 144
  int idx = blockIdx.x * 256 + threadIdx.x;
  if (idx >= NPADW * C8O) return;
  int n = idx / C8O, k = (idx % C8O) * 8;
  pack8 ph;
#pragma unroll
  for (int j = 0; j < 8; ++j) {
    int kk = k + j;           // attn feature index = h*72 + e
    int h = kk / 72, e = kk % 72;
    float val = (n < DMODEL && e < 65) ? Wo[(size_t)(h * 65 + e) * DMODEL + n] : 0.f;
    ph.u[j] = __builtin_bit_cast(ushort_t, __float2bfloat16(val));
  }
  *reinterpret_cast<uint4*>(&th[(size_t)n * KO + k]) = ph.v;
}

// ------- QK GEMM: fp16 2-plane 3-product, 512 threads (8 waves), dbuf issue-early -----
__global__ __launch_bounds__(512, 4) void gemm_qk(const ushort_t* __restrict__ Ahg,
                                                  const ushort_t* __restrict__ Alg,
                                                  const ushort_t* __restrict__ Bhg,
                                                  const ushort_t* __restrict__ Blg,
                                                  float* __restrict__ C, int kdim) {
  __shared__ ushort_t Ah[2][4096], Al[2][4096], Bh[2][4096], Bl[2][4096];
  const int t = threadIdx.x;         // 0..511
  const int w = t >> 6, l = t & 63;  // 8 waves
  int m0, n0;
  tile_map(blockIdx.x, 8, m0, n0);
  const int wm = w >> 2, wn = w & 3;  // 2 x 4
  const int row16 = l & 15, g = l >> 4;

  f32x4 acc[4][2], acc2[4][2];
#pragma unroll
  for (int m = 0; m < 4; ++m)
#pragma unroll
    for (int n = 0; n < 2; ++n) { acc[m][n] = (f32x4){0,0,0,0}; acc2[m][n] = (f32x4){0,0,0,0}; }

  const int chunk = t;               // one 8-u16 chunk per plane per thread
  const int r0 = chunk >> 2;         // 0..127
  const int ch0 = (chunk & 3) ^ ((r0 ^ (r0 >> 2)) & 3);

#define STAGE_QK(K0, BUF)                                                       \
  {                                                                             \
    const size_t ga = (size_t)(m0 + r0) * kdim + (K0) + ch0 * 8;                \
    const size_t gb = (size_t)(n0 + r0) * kdim + (K0) + ch0 * 8;                \
    gload_lds16(Ahg + ga, &Ah[BUF][chunk * 8]);                                 \
    gload_lds16(Alg + ga, &Al[BUF][chunk * 8]);                                 \
    gload_lds16(Bhg + gb, &Bh[BUF][chunk * 8]);                                 \
    gload_lds16(Blg + gb, &Bl[BUF][chunk * 8]);                                 \
  }

  STAGE_QK(0, 0);
  __syncthreads();
  for (int k0 = 0, it = 0; k0 < kdim; k0 += 32, ++it) {
    const int cur = it & 1;
    if (k0 + 32 < kdim) STAGE_QK(k0 + 32, cur ^ 1);
    f16x8 fah[4], fal[4], fbh[2], fbl[2];
#pragma unroll
    for (int f = 0; f < 4; ++f) {
      const int ra = wm * 64 + f * 16 + row16;
      const int ca = (g ^ ((ra ^ (ra >> 2)) & 3)) << 3;
      fah[f] = *(const f16x8*)&Ah[cur][ra * 32 + ca];
      fal[f] = *(const f16x8*)&Al[cur][ra * 32 + ca];
    }
#pragma unroll
    for (int f = 0; f < 2; ++f) {
      const int rb = wn * 32 + f * 16 + row16;
      const int cb = (g ^ ((rb ^ (rb >> 2)) & 3)) << 3;
      fbh[f] = *(const f16x8*)&Bh[cur][rb * 32 + cb];
      fbl[f] = *(const f16x8*)&Bl[cur][rb * 32 + cb];
    }
#pragma unroll
    for (int m = 0; m < 4; ++m)
#pragma unroll
      for (int n = 0; n < 2; ++n) {
        acc[m][n]  = __builtin_amdgcn_mfma_f32_16x16x32_f16(fah[m], fbh[n], acc[m][n], 0, 0, 0);
        acc2[m][n] = __builtin_amdgcn_mfma_f32_16x16x32_f16(fah[m], fbl[n], acc2[m][n], 0, 0, 0);
        acc2[m][n] = __builtin_amdgcn_mfma_f32_16x16x32_f16(fal[m], fbh[n], acc2[m][n], 0, 0, 0);
      }
    __syncthreads();
  }
#undef STAGE_QK

  const float S2 = 1.0f / 4096.0f;
#pragma unroll
  for (int m = 0; m < 4; ++m)
#pragma unroll
    for (int n = 0; n < 2; ++n) {
      const int col = n0 + wn * 32 + n * 16 + row16;
      const int rowb = m0 + wm * 64 + m * 16 + g * 4;
#pragma unroll
      for (int i = 0; i < 4; ++i)
        C[(size_t)(rowb + i) * 1024 + col] = acc[m][n][i] + acc2[m][n][i] * S2;
    }
}

// ------- V GEMM: fp16 hi 1-product, 512 threads (8 waves), fp16 output ----------------
__global__ __launch_bounds__(512, 4) void gemm_v(const ushort_t* __restrict__ Ahg,
                                                 const ushort_t* __restrict__ Bhg,
                                                 ushort_t* __restrict__ Cv, int kdim) {
  __shared__ ushort_t Ah[2][4096], Bh[2][4096];
  const int t = threadIdx.x;
  const int w = t >> 6, l = t & 63;
  int m0, n0;
  tile_map(blockIdx.x, 9, m0, n0);
  const int wm = w >> 2, wn = w & 3;
  const int row16 = l & 15, g = l >> 4;

  f32x4 acc[4][2];
#pragma unroll
  for (int m = 0; m < 4; ++m)
#pragma unroll
    for (int n = 0; n < 2; ++n) acc[m][n] = (f32x4){0,0,0,0};

  const int chunk = t;
  const int r0 = chunk >> 2;
  const int ch0 = (chunk & 3) ^ ((r0 ^ (r0 >> 2)) & 3);

#define STAGE_V(K0, BUF)                                                        \
  {                                                                             \
    const size_t ga = (size_t)(m0 + r0) * kdim + (K0) + ch0 * 8;                \
    const size_t gb = (size_t)(n0 + r0) * kdim + (K0) + ch0 * 8;                \
    gload_lds16(Ahg + ga, &Ah[BUF][chunk * 8]);                                 \
    gload_lds16(Bhg + gb, &Bh[BUF][chunk * 8]);                                 \
  }

  STAGE_V(0, 0);
  __syncthreads();
  for (int k0 = 0, it = 0; k0 < kdim; k0 += 32, ++it) {
    const int cur = it & 1;
    if (k0 + 32 < kdim) STAGE_V(k0 + 32, cur ^ 1);
    f16x8 fah[4], fbh[2];
#pragma unroll
    for (int f = 0; f < 4; ++f) {
      const int ra = wm * 64 + f * 16 + row16;
      const int ca = (g ^ ((ra ^ (ra >> 2)) & 3)) << 3;
      fah[f] = *(const f16x8*)&Ah[cur][ra * 32 + ca];
    }
#pragma unroll
    for (int f = 0; f < 2; ++f) {
      const int rb = wn * 32 + f * 16 + row16;
      const int cb = (g ^ ((rb ^ (rb >> 2)) & 3)) << 3;
      fbh[f] = *(const f16x8*)&Bh[cur][rb * 32 + cb];
    }
#pragma unroll
    for (int m = 0; m < 4; ++m)
#pragma unroll
      for (int n = 0; n < 2; ++n)
        acc[m][n] = __builtin_amdgcn_mfma_f32_16x16x32_f16(fah[m], fbh[n], acc[m][n], 0, 0, 0);
    __syncthreads();
  }
#undef STAGE_V

#pragma unroll
  for (int m = 0; m < 4; ++m)
#pragma unroll
    for (int n = 0; n < 2; ++n) {
      const int col = n0 + wn * 32 + n * 16 + row16;
      const int rowb = m0 + wm * 64 + m * 16 + g * 4;
#pragma unroll
      for (int i = 0; i < 4; ++i)
        Cv[(size_t)(rowb + i) * 1152 + col] =
            __builtin_bit_cast(ushort_t, (_Float16)acc[m][n][i]);
    }
}

// ------- O GEMM: single-plane bf16, 512 threads (8 waves) -----------------------------
__global__ __launch_bounds__(512, 4) void gemm_o(const ushort_t* __restrict__ Ahg,
                                                 const ushort_t* __restrict__ Bhg,
                                                 float* __restrict__ C, int kdim) {
  __shared__ ushort_t Ah[2][4096], Bh[2][4096];
  const int t = threadIdx.x;
  const int w = t >> 6, l = t & 63;
  int m0, n0;
  tile_map(blockIdx.x, 9, m0, n0);
  const int wm = w >> 2, wn = w & 3;
  const int row16 = l & 15, g = l >> 4;

  f32x4 acc[4][2];
#pragma unroll
  for (int m = 0; m < 4; ++m)
#pragma unroll
    for (int n = 0; n < 2; ++n) acc[m][n] = (f32x4){0,0,0,0};

  const int chunk = t;
  const int r0 = chunk >> 2;
  const int ch0 = (chunk & 3) ^ ((r0 ^ (r0 >> 2)) & 3);

#define STAGE_O(K0, BUF)                                                        \
  {                                                                             \
    const size_t ga = (size_t)(m0 + r0) * kdim + (K0) + ch0 * 8;                \
    const size_t gb = (size_t)(n0 + r0) * kdim + (K0) + ch0 * 8;                \
    gload_lds16(Ahg + ga, &Ah[BUF][chunk * 8]);                                 \
    gload_lds16(Bhg + gb, &Bh[BUF][chunk * 8]);                                 \
  }

  STAGE_O(0, 0);
  __syncthreads();
  for (int k0 = 0, it = 0; k0 < kdim; k0 += 32, ++it) {
    const int cur = it & 1;
    if (k0 + 32 < kdim) STAGE_O(k0 + 32, cur ^ 1);
    bf16x8 fah[4], fbh[2];
#pragma unroll
    for (int f = 0; f < 4; ++f) {
      const int ra = wm * 64 + f * 16 + row16;
      const int ca = (g ^ ((ra ^ (ra >> 2)) & 3)) << 3;
      fah[f] = *(const bf16x8*)&Ah[cur][ra * 32 + ca];
    }
#pragma unroll
    for (int f = 0; f < 2; ++f) {
      const int rb = wn * 32 + f * 16 + row16;
      const int cb = (g ^ ((rb ^ (rb >> 2)) & 3)) << 3;
      fbh[f] = *(const bf16x8*)&Bh[cur][rb * 32 + cb];
    }
#pragma unroll
    for (int m = 0; m < 4; ++m)
#pragma unroll
      for (int n = 0; n < 2; ++n)
        acc[m][n] = __builtin_amdgcn_mfma_f32_16x16x32_bf16(fah[m], fbh[n], acc[m][n], 0, 0, 0);
    __syncthreads();
  }
#undef STAGE_O

#pragma unroll
  for (int m = 0; m < 4; ++m)
#pragma unroll
    for (int n = 0; n < 2; ++n) {
      const int col = n0 + wn * 32 + n * 16 + row16;
      if (col < DMODEL) {
        const int rowb = m0 + wm * 64 + m * 16 + g * 4;
#pragma unroll
        for (int i = 0; i < 4; ++i) C[(size_t)(rowb + i) * DMODEL + col] = acc[m][n][i];
      }
    }
}

// ---------------- kv state partials: phi(k)^T @ v per (bh_local, split) ---------------
// 32-row chunks: LDS 17.4KB -> 8 blocks/CU. Each block: 128 rows = 4 chunks.
__global__ __launch_bounds__(256, 8) void kv_kernel(const float* __restrict__ qk,
                                                    const ushort_t* __restrict__ vbuf,
                                                    float* __restrict__ kvpart,
                                                    float* __restrict__ kspart) {
  const int bh = blockIdx.x;    // 0..31 (local)
  const int split = blockIdx.y; // 0..KVSPLIT-1
  const int bl = bh >> 4, h = bh & 15;
  __shared__ float ks[32][68];
  __shared__ float vs[32][68];
  const int tid = threadIdx.x;
  const int t1 = 256 + tid;
  const int d00 = (tid / 17) * 4, e00 = (tid % 17) * 4;
  const int d10 = (t1 / 17) * 4, e10 = (t1 % 17) * 4;
  float acc0[16] = {};
  float acc1[16] = {};
  float kcol = 0.f;

  for (int chunk = 0; chunk < 4; ++chunk) {
    const int nb = split * 128 + chunk * 32;
    for (int idx = tid; idx < 32 * 65; idx += 256) {
      const int r = idx / 65, d = idx % 65;
      const size_t row = (size_t)(bl * S_LEN + nb + r);
      float val;
      if (d == 0) val = 1.f;
      else if (d <= 32) val = qk[row * 1024 + 512 + h * 32 + (d - 1)];
      else {
        float x = qk[row * 1024 + 512 + h * 32 + (d - 33)];
        val = 0.5f * x * x;
      }
      ks[r][d] = val;
      vs[r][d] = (float)__builtin_bit_cast(_Float16, vbuf[row * 1152 + h * 65 + d]);
    }
    __syncthreads();
    for (int r = 0; r < 32; ++r) {
      float a[4], v[4];
#pragma unroll
      for (int i = 0; i < 4; ++i) a[i] = ks[r][d00 + i];
#pragma unroll
      for (int j = 0; j < 4; ++j) v[j] = vs[r][e00 + j];
#pragma unroll
      for (int i = 0; i < 4; ++i)
#pragma unroll
        for (int j = 0; j < 4; ++j) acc0[i * 4 + j] += a[i] * v[j];
    }
    if (tid < 33) {
      for (int r = 0; r < 32; ++r) {
        float a[4], v[4];
#pragma unroll
        for (int i = 0; i < 4; ++i) a[i] = ks[r][d10 + i];
#pragma unroll
        for (int j = 0; j < 4; ++j) v[j] = vs[r][e10 + j];
#pragma unroll
        for (int i = 0; i < 4; ++i)
#pragma unroll
          for (int j = 0; j < 4; ++j) acc1[i * 4 + j] += a[i] * v[j];
      }
    }
    if (tid < 65) {
      float s = 0.f;
      for (int r = 0; r < 32; ++r) s += ks[r][tid];
      kcol += s;
    }
    __syncthreads();
  }

  float* kvp = kvpart + ((size_t)split * 32 + bh) * 4225;
#pragma unroll
  for (int i = 0; i < 4; ++i)
#pragma unroll
    for (int j = 0; j < 4; ++j) {
      int d = d00 + i, e = e00 + j;
      if (d < 65 && e < 65) kvp[d * 65 + e] = acc0[i * 4 + j];
    }
  if (tid < 33) {
#pragma unroll
    for (int i = 0; i < 4; ++i)
#pragma unroll
      for (int j = 0; j < 4; ++j) {
        int d = d10 + i, e = e10 + j;
        if (d < 65 && e < 65) kvp[d * 65 + e] = acc1[i * 4 + j];
      }
  }
  if (tid < 65) kspart[((size_t)split * 32 + bh) * 65 + tid] = kcol;
}

__global__ __launch_bounds__(256) void kv_reduce(const float* __restrict__ kvpart,
                                                 const float* __restrict__ kspart,
                                                 float* __restrict__ kv,
                                                 float* __restrict__ ksum) {
  const int NKV = 32 * 4225;
  const int NKS = 32 * 65;
  int i = blockIdx.x * 256 + threadIdx.x;
  if (i < NKV) {
    float s = 0.f;
#pragma unroll 8
    for (int p = 0; p < KVSPLIT; ++p) s += kvpart[(size_t)p * NKV + i];
    kv[i] = s;
  } else if (i < NKV + NKS) {
    int j = i - NKV;
    float s = 0.f;
#pragma unroll 8
    for (int p = 0; p < KVSPLIT; ++p) s += kspart[p * NKS + j];
    ksum[j] = s;
  }
}

// ------- phi(q)@kv, normalize, mask; write attn bf16 (single plane), k' = h*72+e ------
__global__ __launch_bounds__(256, 6) void qkv_kernel(const float* __restrict__ qk,
                                                     const float* __restrict__ kv,
                                                     const float* __restrict__ ksum,
                                                     const int* __restrict__ mask,
                                                     uint_t* __restrict__ ath32,
                                                     int half) {
  const int gx = blockIdx.x;   // 0..127 (32-token chunks within batch)
  const int bh = blockIdx.y;   // 0..31 local
  const int bl = bh >> 4, h = bh & 15;
  __shared__ float kvs[65 * 68];
  __shared__ float phis[32][68];
  __shared__ float kss[65];
  __shared__ float qsums[32];
  const int tid = threadIdx.x;

  const float* kvp = kv + (size_t)bh * 4225;
  for (int i = tid; i < 4225; i += 256) kvs[(i / 65) * 68 + (i % 65)] = kvp[i];
  for (int idx = tid; idx < 1024; idx += 256) {
    int tt = idx >> 5, f = idx & 31;
    size_t row = (size_t)(bl * S_LEN + gx * 32 + tt);
    float val = qk[row * 1024 + h * 32 + f];
    phis[tt][1 + f] = val;
    phis[tt][33 + f] = 0.5f * val * val;
  }
  if (tid < 32) phis[tid][0] = 1.f;
  if (tid < 65) kss[tid] = ksum[bh * 65 + tid];
  __syncthreads();
  if (tid < 32) {
    float s = 0.f;
    for (int d = 0; d < 65; ++d) s += phis[tid][d];
    qsums[tid] = s;
  }
  __syncthreads();

  const int tt = tid >> 3, fg = tid & 7;
  float accs[8] = {0.f, 0.f, 0.f, 0.f, 0.f, 0.f, 0.f, 0.f};
  const float* ph = phis[tt];
#pragma unroll 4
  for (int d = 0; d < 65; ++d) {
    float p = ph[d];
    const float* kr = &kvs[d * 68 + fg * 8];
    float4 va = *reinterpret_cast<const float4*>(kr);
    float4 vb = *reinterpret_cast<const float4*>(kr + 4);
    accs[0] += p * va.x; accs[1] += p * va.y; accs[2] += p * va.z; accs[3] += p * va.w;
    accs[4] += p * vb.x; accs[5] += p * vb.y; accs[6] += p * vb.z; accs[7] += p * vb.w;
  }
  float a64 = 0.f;
  if (fg == 0) {
#pragma unroll 4
    for (int d = 0; d < 65; ++d) a64 += ph[d] * kvs[d * 68 + 64];
  }

  const int s_in_b = gx * 32 + tt;
  const size_t row = (size_t)(bl * S_LEN + s_in_b);
  const int m = mask[(half * 2 + bl) * S_LEN + s_in_b];
  const float qs = qsums[tt];
  const float fm = (m == 0) ? 0.f : 1.f;
  float o[8];
#pragma unroll
  for (int j = 0; j < 8; ++j) {
    float z = qs * kss[fg * 8 + j] + 1e-9f;
    o[j] = fm * accs[j] / z;
  }
  const size_t base = row * 576 + h * 36 + fg * 4;  // u32 units; row = 1152 u16
  pack8 phh;
#pragma unroll
  for (int j = 0; j < 8; ++j)
    phh.u[j] = __builtin_bit_cast(ushort_t, __float2bfloat16(o[j]));
  *reinterpret_cast<uint4*>(&ath32[base]) = phh.v;
  if (fg == 0) {
    float z = qs * kss[64] + 1e-9f;
    float o64 = fm * a64 / z;
    uint4 tailh = {(uint_t)__builtin_bit_cast(ushort_t, __float2bfloat16(o64)), 0u, 0u, 0u};
    *reinterpret_cast<uint4*>(&ath32[row * 576 + h * 36 + 32]) = tailh;
  }
}

extern "C" void kernel_launch(void* const* d_in, const int* in_sizes, int n_in,
                              void* d_out, int out_size, void* d_ws, size_t ws_size,
                              hipStream_t stream) {
  const float* hs = (const float*)d_in[0];
  const int* mask = (const int*)d_in[1];
  const float* Wq = (const float*)d_in[2];
  const float* Wk = (const float*)d_in[3];
  const float* Wv = (const float*)d_in[4];
  const float* Wo = (const float*)d_in[5];
  float* out = (float*)d_out;

  const size_t PLANE_HS = (size_t)M_H * KPAD;    // u16 per hs plane (8.65M)

  char* base = (char*)d_ws;
  // region 1: hs hi/lo planes (34.6 MB); attn bf16 plane (18.9 MB) aliases it later
  ushort_t* hsh = (ushort_t*)base;
  ushort_t* hsl = hsh + PLANE_HS;
  uint_t* ath32 = (uint_t*)base;
  char* b1 = base + 2 * PLANE_HS * 2;
  float* qkbuf = (float*)b1;                     // [M_H][1024] f32 : 33.6 MB
  char* b2 = b1 + (size_t)M_H * 1024 * 4;
  ushort_t* vbuf = (ushort_t*)b2;                // [M_H][1152] fp16 : 18.9 MB
  char* b3 = b2 + (size_t)M_H * 1152 * 2;
  float* kv = (float*)b3;
  float* ksum = kv + 32 * 4225;
  float* kvpart = ksum + 32 * 65;                // KVSPLIT * 32 * 4225
  float* kspart = kvpart + (size_t)KVSPLIT * 32 * 4225;
  char* b4 = b3 + ((size_t)(32 * 4225 + 32 * 65) * (KVSPLIT + 1)) * 4;
  ushort_t* Wqkh = (ushort_t*)b4;                // [1024][1056] fp16 hi
  ushort_t* Wqkl = Wqkh + (size_t)1024 * KPAD;   // lo
  ushort_t* Wvh = Wqkl + (size_t)1024 * KPAD;    // [1152][1056] fp16 hi
  ushort_t* Woh = Wvh + (size_t)NPADW * KPAD;    // [1152][1152] bf16

  dim3 blk(256);
  const int C8 = KPAD / 8;
  const int C8O = KO / 8;

  split_wqk_kernel<<<(1024 * C8 + 255) / 256, blk, 0, stream>>>(Wq, Wk, Wqkh, Wqkl);
  split_wv_kernel<<<(NPADW * C8 + 255) / 256, blk, 0, stream>>>(Wv, Wvh);
  split_wo_kernel<<<(NPADW * C8O + 255) / 256, blk, 0, stream>>>(Wo, Woh);

  for (int half = 0; half < 2; ++half) {
    const float* hs_h = hs + (size_t)half * M_H * DMODEL;
    float* out_h = out + (size_t)half * M_H * DMODEL;

    split_hs_kernel<<<(M_H * C8 + 255) / 256, blk, 0, stream>>>(hs_h, hsh, hsl);

    // q|k projection: fp32-grade 3-product fp16; 512 blocks x 512 threads (8 waves)
    gemm_qk<<<512, dim3(512), 0, stream>>>(hsh, hsl, Wqkh, Wqkl, qkbuf, KPAD);
    // v projection: 1-product fp16, 512 threads, fp16 output
    gemm_v<<<576, dim3(512), 0, stream>>>(hsh, Wvh, vbuf, KPAD);

    kv_kernel<<<dim3(32, KVSPLIT), blk, 0, stream>>>(qkbuf, vbuf, kvpart, kspart);
    kv_reduce<<<dim3((32 * 4225 + 32 * 65 + 255) / 256), blk, 0, stream>>>(kvpart, kspart, kv, ksum);

    qkv_kernel<<<dim3(128, 32), blk, 0, stream>>>(qkbuf, kv, ksum, mask, ath32, half);

    gemm_o<<<576, dim3(512), 0, stream>>>((ushort_t*)ath32, Woh, out_h, KO);
  }
}

// Round 12
// 488.382 us; speedup vs baseline: 2.9122x; 2.9122x over previous
//
#include <hip/hip_runtime.h>
#include <hip/hip_bf16.h>

typedef unsigned short ushort_t;
typedef unsigned int uint_t;

#define S_LEN 4096
#define BATCH 4
#define DMODEL 1040
#define KPAD 1056          // 1040 padded to 33*32 (hs K)
#define KO 1152            // attn feature dim: 16 heads * 72; O-GEMM K
#define NPADW 1152
#define M_H 8192           // rows per half (2 batches)
#define KVSPLIT 32         // kv-state split count

using f32x4 = __attribute__((ext_vector_type(4))) float;
using bf16x8 = __attribute__((ext_vector_type(8))) __bf16;
using f16x8 = __attribute__((ext_vector_type(8))) _Float16;

// fp16 two-plane split, lo plane pre-scaled by 2^12
__device__ __forceinline__ void splitf16(float x, ushort_t& h, ushort_t& l) {
  _Float16 hf = (_Float16)x;
  float r = (x - (float)hf) * 4096.0f;
  _Float16 lf = (_Float16)r;
  h = __builtin_bit_cast(ushort_t, hf);
  l = __builtin_bit_cast(ushort_t, lf);
}

typedef const __attribute__((address_space(1))) unsigned int* gas_u32p;
typedef __attribute__((address_space(3))) unsigned int* las_u32p;
__device__ __forceinline__ void gload_lds16(const ushort_t* g, ushort_t* l) {
  __builtin_amdgcn_global_load_lds((gas_u32p)g, (las_u32p)l, 16, 0, 0);
}

// XCD-chunked tile map: XCD x owns m-panels [x*8, x*8+8), n-inner order.
__device__ __forceinline__ void tile_map(int lid, int NT, int& m0, int& n0) {
  const int x = lid & 7, pos = lid >> 3;
  const int mi = pos / NT, ni = pos - mi * NT;
  m0 = (x * 8 + mi) * 128;
  n0 = ni * 128;
}

union pack8 { ushort_t u[8]; uint4 v; };

// ---------------- split hs rows [M_H][1040] f32 -> fp16 h/l' planes [M_H][KPAD] -------
__global__ __launch_bounds__(256) void split_hs_kernel(const float* __restrict__ hs,
                                                       ushort_t* __restrict__ hh,
                                                       ushort_t* __restrict__ hl) {
  const int C8 = KPAD / 8;  // 132
  int idx = blockIdx.x * 256 + threadIdx.x;
  if (idx >= M_H * C8) return;
  int row = idx / C8, col = (idx % C8) * 8;
  pack8 ph, pl;
  if (col < DMODEL) {
    const float* p = &hs[(size_t)row * DMODEL + col];
#pragma unroll
    for (int j = 0; j < 8; ++j) splitf16(p[j], ph.u[j], pl.u[j]);
  } else {
#pragma unroll
    for (int j = 0; j < 8; ++j) { ph.u[j] = 0; pl.u[j] = 0; }
  }
  size_t o = (size_t)row * KPAD + col;
  *reinterpret_cast<uint4*>(&hh[o]) = ph.v;
  *reinterpret_cast<uint4*>(&hl[o]) = pl.v;
}

// ------- Wq||Wk transpose+split (fp16 scaled): Wt[n<1024][k<1056] ---------------------
__global__ __launch_bounds__(256) void split_wqk_kernel(const float* __restrict__ Wq,
                                                        const float* __restrict__ Wk,
                                                        ushort_t* __restrict__ th,
                                                        ushort_t* __restrict__ tl) {
  const int C8 = KPAD / 8;
  int idx = blockIdx.x * 256 + threadIdx.x;
  if (idx >= 1024 * C8) return;
  int n = idx / C8, k = (idx % C8) * 8;
  pack8 ph, pl;
#pragma unroll
  for (int j = 0; j < 8; ++j) {
    int kk = k + j;
    float val = 0.f;
    if (kk < DMODEL) val = (n < 512) ? Wq[(size_t)kk * 512 + n] : Wk[(size_t)kk * 512 + (n - 512)];
    splitf16(val, ph.u[j], pl.u[j]);
  }
  size_t o = (size_t)n * KPAD + k;
  *reinterpret_cast<uint4*>(&th[o]) = ph.v;
  *reinterpret_cast<uint4*>(&tl[o]) = pl.v;
}

// ------- Wv transpose (fp16 hi only): Wt[n<1152][k<1056] ------------------------------
__global__ __launch_bounds__(256) void split_wv_kernel(const float* __restrict__ Wv,
                                                       ushort_t* __restrict__ th) {
  const int C8 = KPAD / 8;
  int idx = blockIdx.x * 256 + threadIdx.x;
  if (idx >= NPADW * C8) return;
  int n = idx / C8, k = (idx % C8) * 8;
  pack8 ph;
#pragma unroll
  for (int j = 0; j < 8; ++j) {
    int kk = k + j;
    float val = (n < DMODEL && kk < DMODEL) ? Wv[(size_t)kk * DMODEL + n] : 0.f;
    ph.u[j] = __builtin_bit_cast(ushort_t, (_Float16)val);
  }
  *reinterpret_cast<uint4*>(&th[(size_t)n * KPAD + k]) = ph.v;
}

// ------- Wo transpose (bf16 single plane) with attn k-mapping k' = h*72+e -------------
__global__ __launch_bounds__(256) void split_wo_kernel(const float* __restrict__ Wo,
                                                       ushort_t* __restrict__ th) {
  const int C8O = KO / 8;  // 144
  int idx = blockIdx.x * 256 + threadIdx.x;
  if (idx >= NPADW * C8O) return;
  int n = idx / C8O, k = (idx % C8O) * 8;
  pack8 ph;
#pragma unroll
  for (int j = 0; j < 8; ++j) {
    int kk = k + j;           // attn feature index = h*72 + e
    int h = kk / 72, e = kk % 72;
    float val = (n < DMODEL && e < 65) ? Wo[(size_t)(h * 65 + e) * DMODEL + n] : 0.f;
    ph.u[j] = __builtin_bit_cast(ushort_t, __float2bfloat16(val));
  }
  *reinterpret_cast<uint4*>(&th[(size_t)n * KO + k]) = ph.v;
}

// ------- QK GEMM: fp16 2-plane 3-product, 512 threads (8 waves), dbuf issue-early -----
__global__ __launch_bounds__(512, 4) void gemm_qk(const ushort_t* __restrict__ Ahg,
                                                  const ushort_t* __restrict__ Alg,
                                                  const ushort_t* __restrict__ Bhg,
                                                  const ushort_t* __restrict__ Blg,
                                                  float* __restrict__ C, int kdim) {
  __shared__ ushort_t Ah[2][4096], Al[2][4096], Bh[2][4096], Bl[2][4096];
  const int t = threadIdx.x;         // 0..511
  const int w = t >> 6, l = t & 63;  // 8 waves
  int m0, n0;
  tile_map(blockIdx.x, 8, m0, n0);
  const int wm = w >> 2, wn = w & 3;  // 2 x 4
  const int row16 = l & 15, g = l >> 4;

  f32x4 acc[4][2], acc2[4][2];
#pragma unroll
  for (int m = 0; m < 4; ++m)
#pragma unroll
    for (int n = 0; n < 2; ++n) { acc[m][n] = (f32x4){0,0,0,0}; acc2[m][n] = (f32x4){0,0,0,0}; }

  const int chunk = t;               // one 8-u16 chunk per plane per thread
  const int r0 = chunk >> 2;         // 0..127
  const int ch0 = (chunk & 3) ^ ((r0 ^ (r0 >> 2)) & 3);

#define STAGE_QK(K0, BUF)                                                       \
  {                                                                             \
    const size_t ga = (size_t)(m0 + r0) * kdim + (K0) + ch0 * 8;                \
    const size_t gb = (size_t)(n0 + r0) * kdim + (K0) + ch0 * 8;                \
    gload_lds16(Ahg + ga, &Ah[BUF][chunk * 8]);                                 \
    gload_lds16(Alg + ga, &Al[BUF][chunk * 8]);                                 \
    gload_lds16(Bhg + gb, &Bh[BUF][chunk * 8]);                                 \
    gload_lds16(Blg + gb, &Bl[BUF][chunk * 8]);                                 \
  }

  STAGE_QK(0, 0);
  __syncthreads();
  for (int k0 = 0, it = 0; k0 < kdim; k0 += 32, ++it) {
    const int cur = it & 1;
    if (k0 + 32 < kdim) STAGE_QK(k0 + 32, cur ^ 1);
    f16x8 fah[4], fal[4], fbh[2], fbl[2];
#pragma unroll
    for (int f = 0; f < 4; ++f) {
      const int ra = wm * 64 + f * 16 + row16;
      const int ca = (g ^ ((ra ^ (ra >> 2)) & 3)) << 3;
      fah[f] = *(const f16x8*)&Ah[cur][ra * 32 + ca];
      fal[f] = *(const f16x8*)&Al[cur][ra * 32 + ca];
    }
#pragma unroll
    for (int f = 0; f < 2; ++f) {
      const int rb = wn * 32 + f * 16 + row16;
      const int cb = (g ^ ((rb ^ (rb >> 2)) & 3)) << 3;
      fbh[f] = *(const f16x8*)&Bh[cur][rb * 32 + cb];
      fbl[f] = *(const f16x8*)&Bl[cur][rb * 32 + cb];
    }
#pragma unroll
    for (int m = 0; m < 4; ++m)
#pragma unroll
      for (int n = 0; n < 2; ++n) {
        acc[m][n]  = __builtin_amdgcn_mfma_f32_16x16x32_f16(fah[m], fbh[n], acc[m][n], 0, 0, 0);
        acc2[m][n] = __builtin_amdgcn_mfma_f32_16x16x32_f16(fah[m], fbl[n], acc2[m][n], 0, 0, 0);
        acc2[m][n] = __builtin_amdgcn_mfma_f32_16x16x32_f16(fal[m], fbh[n], acc2[m][n], 0, 0, 0);
      }
    __syncthreads();
  }
#undef STAGE_QK

  const float S2 = 1.0f / 4096.0f;
#pragma unroll
  for (int m = 0; m < 4; ++m)
#pragma unroll
    for (int n = 0; n < 2; ++n) {
      const int col = n0 + wn * 32 + n * 16 + row16;
      const int rowb = m0 + wm * 64 + m * 16 + g * 4;
#pragma unroll
      for (int i = 0; i < 4; ++i)
        C[(size_t)(rowb + i) * 1024 + col] = acc[m][n][i] + acc2[m][n][i] * S2;
    }
}

// ------- V GEMM: fp16 hi 1-product, 512 threads (8 waves), fp16 output ----------------
__global__ __launch_bounds__(512, 4) void gemm_v(const ushort_t* __restrict__ Ahg,
                                                 const ushort_t* __restrict__ Bhg,
                                                 ushort_t* __restrict__ Cv, int kdim) {
  __shared__ ushort_t Ah[2][4096], Bh[2][4096];
  const int t = threadIdx.x;
  const int w = t >> 6, l = t & 63;
  int m0, n0;
  tile_map(blockIdx.x, 9, m0, n0);
  const int wm = w >> 2, wn = w & 3;
  const int row16 = l & 15, g = l >> 4;

  f32x4 acc[4][2];
#pragma unroll
  for (int m = 0; m < 4; ++m)
#pragma unroll
    for (int n = 0; n < 2; ++n) acc[m][n] = (f32x4){0,0,0,0};

  const int chunk = t;
  const int r0 = chunk >> 2;
  const int ch0 = (chunk & 3) ^ ((r0 ^ (r0 >> 2)) & 3);

#define STAGE_V(K0, BUF)                                                        \
  {                                                                             \
    const size_t ga = (size_t)(m0 + r0) * kdim + (K0) + ch0 * 8;                \
    const size_t gb = (size_t)(n0 + r0) * kdim + (K0) + ch0 * 8;                \
    gload_lds16(Ahg + ga, &Ah[BUF][chunk * 8]);                                 \
    gload_lds16(Bhg + gb, &Bh[BUF][chunk * 8]);                                 \
  }

  STAGE_V(0, 0);
  __syncthreads();
  for (int k0 = 0, it = 0; k0 < kdim; k0 += 32, ++it) {
    const int cur = it & 1;
    if (k0 + 32 < kdim) STAGE_V(k0 + 32, cur ^ 1);
    f16x8 fah[4], fbh[2];
#pragma unroll
    for (int f = 0; f < 4; ++f) {
      const int ra = wm * 64 + f * 16 + row16;
      const int ca = (g ^ ((ra ^ (ra >> 2)) & 3)) << 3;
      fah[f] = *(const f16x8*)&Ah[cur][ra * 32 + ca];
    }
#pragma unroll
    for (int f = 0; f < 2; ++f) {
      const int rb = wn * 32 + f * 16 + row16;
      const int cb = (g ^ ((rb ^ (rb >> 2)) & 3)) << 3;
      fbh[f] = *(const f16x8*)&Bh[cur][rb * 32 + cb];
    }
#pragma unroll
    for (int m = 0; m < 4; ++m)
#pragma unroll
      for (int n = 0; n < 2; ++n)
        acc[m][n] = __builtin_amdgcn_mfma_f32_16x16x32_f16(fah[m], fbh[n], acc[m][n], 0, 0, 0);
    __syncthreads();
  }
#undef STAGE_V

#pragma unroll
  for (int m = 0; m < 4; ++m)
#pragma unroll
    for (int n = 0; n < 2; ++n) {
      const int col = n0 + wn * 32 + n * 16 + row16;
      const int rowb = m0 + wm * 64 + m * 16 + g * 4;
#pragma unroll
      for (int i = 0; i < 4; ++i)
        Cv[(size_t)(rowb + i) * 1152 + col] =
            __builtin_bit_cast(ushort_t, (_Float16)acc[m][n][i]);
    }
}

// ------- O GEMM: single-plane bf16, 512 threads (8 waves) -----------------------------
__global__ __launch_bounds__(512, 4) void gemm_o(const ushort_t* __restrict__ Ahg,
                                                 const ushort_t* __restrict__ Bhg,
                                                 float* __restrict__ C, int kdim) {
  __shared__ ushort_t Ah[2][4096], Bh[2][4096];
  const int t = threadIdx.x;
  const int w = t >> 6, l = t & 63;
  int m0, n0;
  tile_map(blockIdx.x, 9, m0, n0);
  const int wm = w >> 2, wn = w & 3;
  const int row16 = l & 15, g = l >> 4;

  f32x4 acc[4][2];
#pragma unroll
  for (int m = 0; m < 4; ++m)
#pragma unroll
    for (int n = 0; n < 2; ++n) acc[m][n] = (f32x4){0,0,0,0};

  const int chunk = t;
  const int r0 = chunk >> 2;
  const int ch0 = (chunk & 3) ^ ((r0 ^ (r0 >> 2)) & 3);

#define STAGE_O(K0, BUF)                                                        \
  {                                                                             \
    const size_t ga = (size_t)(m0 + r0) * kdim + (K0) + ch0 * 8;                \
    const size_t gb = (size_t)(n0 + r0) * kdim + (K0) + ch0 * 8;                \
    gload_lds16(Ahg + ga, &Ah[BUF][chunk * 8]);                                 \
    gload_lds16(Bhg + gb, &Bh[BUF][chunk * 8]);                                 \
  }

  STAGE_O(0, 0);
  __syncthreads();
  for (int k0 = 0, it = 0; k0 < kdim; k0 += 32, ++it) {
    const int cur = it & 1;
    if (k0 + 32 < kdim) STAGE_O(k0 + 32, cur ^ 1);
    bf16x8 fah[4], fbh[2];
#pragma unroll
    for (int f = 0; f < 4; ++f) {
      const int ra = wm * 64 + f * 16 + row16;
      const int ca = (g ^ ((ra ^ (ra >> 2)) & 3)) << 3;
      fah[f] = *(const bf16x8*)&Ah[cur][ra * 32 + ca];
    }
#pragma unroll
    for (int f = 0; f < 2; ++f) {
      const int rb = wn * 32 + f * 16 + row16;
      const int cb = (g ^ ((rb ^ (rb >> 2)) & 3)) << 3;
      fbh[f] = *(const bf16x8*)&Bh[cur][rb * 32 + cb];
    }
#pragma unroll
    for (int m = 0; m < 4; ++m)
#pragma unroll
      for (int n = 0; n < 2; ++n)
        acc[m][n] = __builtin_amdgcn_mfma_f32_16x16x32_bf16(fah[m], fbh[n], acc[m][n], 0, 0, 0);
    __syncthreads();
  }
#undef STAGE_O

#pragma unroll
  for (int m = 0; m < 4; ++m)
#pragma unroll
    for (int n = 0; n < 2; ++n) {
      const int col = n0 + wn * 32 + n * 16 + row16;
      if (col < DMODEL) {
        const int rowb = m0 + wm * 64 + m * 16 + g * 4;
#pragma unroll
        for (int i = 0; i < 4; ++i) C[(size_t)(rowb + i) * DMODEL + col] = acc[m][n][i];
      }
    }
}

// ---------------- kv state partials: phi(k)^T @ v per (bh_local, split) ---------------
// ROUND-10 version: 64-row chunks, 34.8KB LDS -> 4 blocks/CU, VGPR 52 (NO min-wave
// clamp — round 11's (256,8) clamp forced VGPR=32 and spilled the 33-float acc state
// to scratch: 1.6 GB of HBM traffic, 505 us. Do not re-add.)
__global__ __launch_bounds__(256) void kv_kernel(const float* __restrict__ qk,
                                                 const ushort_t* __restrict__ vbuf,
                                                 float* __restrict__ kvpart,
                                                 float* __restrict__ kspart) {
  const int bh = blockIdx.x;    // 0..31 (local)
  const int split = blockIdx.y; // 0..KVSPLIT-1
  const int bl = bh >> 4, h = bh & 15;
  __shared__ float ks[64][68];
  __shared__ float vs[64][68];
  const int tid = threadIdx.x;
  const int t1 = 256 + tid;
  const int d00 = (tid / 17) * 4, e00 = (tid % 17) * 4;
  const int d10 = (t1 / 17) * 4, e10 = (t1 % 17) * 4;
  float acc0[16] = {};
  float acc1[16] = {};
  float kcol = 0.f;

  for (int chunk = 0; chunk < 2; ++chunk) {
    const int nb = split * 128 + chunk * 64;
    for (int idx = tid; idx < 64 * 65; idx += 256) {
      const int r = idx / 65, d = idx % 65;
      const size_t row = (size_t)(bl * S_LEN + nb + r);
      float val;
      if (d == 0) val = 1.f;
      else if (d <= 32) val = qk[row * 1024 + 512 + h * 32 + (d - 1)];
      else {
        float x = qk[row * 1024 + 512 + h * 32 + (d - 33)];
        val = 0.5f * x * x;
      }
      ks[r][d] = val;
      vs[r][d] = (float)__builtin_bit_cast(_Float16, vbuf[row * 1152 + h * 65 + d]);
    }
    __syncthreads();
    for (int r = 0; r < 64; ++r) {
      float a[4], v[4];
#pragma unroll
      for (int i = 0; i < 4; ++i) a[i] = ks[r][d00 + i];
#pragma unroll
      for (int j = 0; j < 4; ++j) v[j] = vs[r][e00 + j];
#pragma unroll
      for (int i = 0; i < 4; ++i)
#pragma unroll
        for (int j = 0; j < 4; ++j) acc0[i * 4 + j] += a[i] * v[j];
    }
    if (tid < 33) {
      for (int r = 0; r < 64; ++r) {
        float a[4], v[4];
#pragma unroll
        for (int i = 0; i < 4; ++i) a[i] = ks[r][d10 + i];
#pragma unroll
        for (int j = 0; j < 4; ++j) v[j] = vs[r][e10 + j];
#pragma unroll
        for (int i = 0; i < 4; ++i)
#pragma unroll
          for (int j = 0; j < 4; ++j) acc1[i * 4 + j] += a[i] * v[j];
      }
    }
    if (tid < 65) {
      float s = 0.f;
      for (int r = 0; r < 64; ++r) s += ks[r][tid];
      kcol += s;
    }
    __syncthreads();
  }

  float* kvp = kvpart + ((size_t)split * 32 + bh) * 4225;
#pragma unroll
  for (int i = 0; i < 4; ++i)
#pragma unroll
    for (int j = 0; j < 4; ++j) {
      int d = d00 + i, e = e00 + j;
      if (d < 65 && e < 65) kvp[d * 65 + e] = acc0[i * 4 + j];
    }
  if (tid < 33) {
#pragma unroll
    for (int i = 0; i < 4; ++i)
#pragma unroll
      for (int j = 0; j < 4; ++j) {
        int d = d10 + i, e = e10 + j;
        if (d < 65 && e < 65) kvp[d * 65 + e] = acc1[i * 4 + j];
      }
  }
  if (tid < 65) kspart[((size_t)split * 32 + bh) * 65 + tid] = kcol;
}

__global__ __launch_bounds__(256) void kv_reduce(const float* __restrict__ kvpart,
                                                 const float* __restrict__ kspart,
                                                 float* __restrict__ kv,
                                                 float* __restrict__ ksum) {
  const int NKV = 32 * 4225;
  const int NKS = 32 * 65;
  int i = blockIdx.x * 256 + threadIdx.x;
  if (i < NKV) {
    float s = 0.f;
#pragma unroll 8
    for (int p = 0; p < KVSPLIT; ++p) s += kvpart[(size_t)p * NKV + i];
    kv[i] = s;
  } else if (i < NKV + NKS) {
    int j = i - NKV;
    float s = 0.f;
#pragma unroll 8
    for (int p = 0; p < KVSPLIT; ++p) s += kspart[p * NKS + j];
    ksum[j] = s;
  }
}

// ------- phi(q)@kv, normalize, mask; write attn bf16 (single plane), k' = h*72+e ------
__global__ __launch_bounds__(256, 6) void qkv_kernel(const float* __restrict__ qk,
                                                     const float* __restrict__ kv,
                                                     const float* __restrict__ ksum,
                                                     const int* __restrict__ mask,
                                                     uint_t* __restrict__ ath32,
                                                     int half) {
  const int gx = blockIdx.x;   // 0..127 (32-token chunks within batch)
  const int bh = blockIdx.y;   // 0..31 local
  const int bl = bh >> 4, h = bh & 15;
  __shared__ float kvs[65 * 68];
  __shared__ float phis[32][68];
  __shared__ float kss[65];
  __shared__ float qsums[32];
  const int tid = threadIdx.x;

  const float* kvp = kv + (size_t)bh * 4225;
  for (int i = tid; i < 4225; i += 256) kvs[(i / 65) * 68 + (i % 65)] = kvp[i];
  for (int idx = tid; idx < 1024; idx += 256) {
    int tt = idx >> 5, f = idx & 31;
    size_t row = (size_t)(bl * S_LEN + gx * 32 + tt);
    float val = qk[row * 1024 + h * 32 + f];
    phis[tt][1 + f] = val;
    phis[tt][33 + f] = 0.5f * val * val;
  }
  if (tid < 32) phis[tid][0] = 1.f;
  if (tid < 65) kss[tid] = ksum[bh * 65 + tid];
  __syncthreads();
  if (tid < 32) {
    float s = 0.f;
    for (int d = 0; d < 65; ++d) s += phis[tid][d];
    qsums[tid] = s;
  }
  __syncthreads();

  const int tt = tid >> 3, fg = tid & 7;
  float accs[8] = {0.f, 0.f, 0.f, 0.f, 0.f, 0.f, 0.f, 0.f};
  const float* ph = phis[tt];
#pragma unroll 4
  for (int d = 0; d < 65; ++d) {
    float p = ph[d];
    const float* kr = &kvs[d * 68 + fg * 8];
    float4 va = *reinterpret_cast<const float4*>(kr);
    float4 vb = *reinterpret_cast<const float4*>(kr + 4);
    accs[0] += p * va.x; accs[1] += p * va.y; accs[2] += p * va.z; accs[3] += p * va.w;
    accs[4] += p * vb.x; accs[5] += p * vb.y; accs[6] += p * vb.z; accs[7] += p * vb.w;
  }
  float a64 = 0.f;
  if (fg == 0) {
#pragma unroll 4
    for (int d = 0; d < 65; ++d) a64 += ph[d] * kvs[d * 68 + 64];
  }

  const int s_in_b = gx * 32 + tt;
  const size_t row = (size_t)(bl * S_LEN + s_in_b);
  const int m = mask[(half * 2 + bl) * S_LEN + s_in_b];
  const float qs = qsums[tt];
  const float fm = (m == 0) ? 0.f : 1.f;
  float o[8];
#pragma unroll
  for (int j = 0; j < 8; ++j) {
    float z = qs * kss[fg * 8 + j] + 1e-9f;
    o[j] = fm * accs[j] / z;
  }
  const size_t base = row * 576 + h * 36 + fg * 4;  // u32 units; row = 1152 u16
  pack8 phh;
#pragma unroll
  for (int j = 0; j < 8; ++j)
    phh.u[j] = __builtin_bit_cast(ushort_t, __float2bfloat16(o[j]));
  *reinterpret_cast<uint4*>(&ath32[base]) = phh.v;
  if (fg == 0) {
    float z = qs * kss[64] + 1e-9f;
    float o64 = fm * a64 / z;
    uint4 tailh = {(uint_t)__builtin_bit_cast(ushort_t, __float2bfloat16(o64)), 0u, 0u, 0u};
    *reinterpret_cast<uint4*>(&ath32[row * 576 + h * 36 + 32]) = tailh;
  }
}

extern "C" void kernel_launch(void* const* d_in, const int* in_sizes, int n_in,
                              void* d_out, int out_size, void* d_ws, size_t ws_size,
                              hipStream_t stream) {
  const float* hs = (const float*)d_in[0];
  const int* mask = (const int*)d_in[1];
  const float* Wq = (const float*)d_in[2];
  const float* Wk = (const float*)d_in[3];
  const float* Wv = (const float*)d_in[4];
  const float* Wo = (const float*)d_in[5];
  float* out = (float*)d_out;

  const size_t PLANE_HS = (size_t)M_H * KPAD;    // u16 per hs plane (8.65M)

  char* base = (char*)d_ws;
  // region 1: hs hi/lo planes (34.6 MB); attn bf16 plane (18.9 MB) aliases it later
  ushort_t* hsh = (ushort_t*)base;
  ushort_t* hsl = hsh + PLANE_HS;
  uint_t* ath32 = (uint_t*)base;
  char* b1 = base + 2 * PLANE_HS * 2;
  float* qkbuf = (float*)b1;                     // [M_H][1024] f32 : 33.6 MB
  char* b2 = b1 + (size_t)M_H * 1024 * 4;
  ushort_t* vbuf = (ushort_t*)b2;                // [M_H][1152] fp16 : 18.9 MB
  char* b3 = b2 + (size_t)M_H * 1152 * 2;
  float* kv = (float*)b3;
  float* ksum = kv + 32 * 4225;
  float* kvpart = ksum + 32 * 65;                // KVSPLIT * 32 * 4225
  float* kspart = kvpart + (size_t)KVSPLIT * 32 * 4225;
  char* b4 = b3 + ((size_t)(32 * 4225 + 32 * 65) * (KVSPLIT + 1)) * 4;
  ushort_t* Wqkh = (ushort_t*)b4;                // [1024][1056] fp16 hi
  ushort_t* Wqkl = Wqkh + (size_t)1024 * KPAD;   // lo
  ushort_t* Wvh = Wqkl + (size_t)1024 * KPAD;    // [1152][1056] fp16 hi
  ushort_t* Woh = Wvh + (size_t)NPADW * KPAD;    // [1152][1152] bf16

  dim3 blk(256);
  const int C8 = KPAD / 8;
  const int C8O = KO / 8;

  split_wqk_kernel<<<(1024 * C8 + 255) / 256, blk, 0, stream>>>(Wq, Wk, Wqkh, Wqkl);
  split_wv_kernel<<<(NPADW * C8 + 255) / 256, blk, 0, stream>>>(Wv, Wvh);
  split_wo_kernel<<<(NPADW * C8O + 255) / 256, blk, 0, stream>>>(Wo, Woh);

  for (int half = 0; half < 2; ++half) {
    const float* hs_h = hs + (size_t)half * M_H * DMODEL;
    float* out_h = out + (size_t)half * M_H * DMODEL;

    split_hs_kernel<<<(M_H * C8 + 255) / 256, blk, 0, stream>>>(hs_h, hsh, hsl);

    // q|k projection: fp32-grade 3-product fp16; 512 blocks x 512 threads (8 waves)
    gemm_qk<<<512, dim3(512), 0, stream>>>(hsh, hsl, Wqkh, Wqkl, qkbuf, KPAD);
    // v projection: 1-product fp16, 512 threads, fp16 output
    gemm_v<<<576, dim3(512), 0, stream>>>(hsh, Wvh, vbuf, KPAD);

    kv_kernel<<<dim3(32, KVSPLIT), blk, 0, stream>>>(qkbuf, vbuf, kvpart, kspart);
    kv_reduce<<<dim3((32 * 4225 + 32 * 65 + 255) / 256), blk, 0, stream>>>(kvpart, kspart, kv, ksum);

    qkv_kernel<<<dim3(128, 32), blk, 0, stream>>>(qkbuf, kv, ksum, mask, ath32, half);

    gemm_o<<<576, dim3(512), 0, stream>>>((ushort_t*)ath32, Woh, out_h, KO);
  }
}

// Round 13
// 461.553 us; speedup vs baseline: 3.0814x; 1.0581x over previous
//
#include <hip/hip_runtime.h>
#include <hip/hip_bf16.h>

typedef unsigned short ushort_t;
typedef unsigned int uint_t;

#define S_LEN 4096
#define BATCH 4
#define DMODEL 1040
#define KPAD 1056          // 1040 padded to 33*32 (hs K)
#define KO 1152            // attn feature dim: 16 heads * 72; O-GEMM K
#define NPADW 1152
#define M_TOK 16384        // full M (4 batches x 4096)
#define KVSPLIT 16         // kv-state split count (16 x 64 bh = 1024 blocks)

using f32x4 = __attribute__((ext_vector_type(4))) float;
using bf16x8 = __attribute__((ext_vector_type(8))) __bf16;
using f16x8 = __attribute__((ext_vector_type(8))) _Float16;

// fp16 two-plane split, lo plane pre-scaled by 2^12
__device__ __forceinline__ void splitf16(float x, ushort_t& h, ushort_t& l) {
  _Float16 hf = (_Float16)x;
  float r = (x - (float)hf) * 4096.0f;
  _Float16 lf = (_Float16)r;
  h = __builtin_bit_cast(ushort_t, hf);
  l = __builtin_bit_cast(ushort_t, lf);
}

typedef const __attribute__((address_space(1))) unsigned int* gas_u32p;
typedef __attribute__((address_space(3))) unsigned int* las_u32p;
__device__ __forceinline__ void gload_lds16(const ushort_t* g, ushort_t* l) {
  __builtin_amdgcn_global_load_lds((gas_u32p)g, (las_u32p)l, 16, 0, 0);
}

// XCD-chunked tile map: XCD x owns m-panels [x*PPX, x*PPX+PPX), n-inner order.
__device__ __forceinline__ void tile_map(int lid, int NT, int PPX, int& m0, int& n0) {
  const int x = lid & 7, pos = lid >> 3;
  const int mi = pos / NT, ni = pos - mi * NT;
  m0 = (x * PPX + mi) * 128;
  n0 = ni * 128;
}

union pack8 { ushort_t u[8]; uint4 v; };

// ---------------- split hs rows [M_TOK][1040] f32 -> fp16 h/l' planes [M_TOK][KPAD] ---
__global__ __launch_bounds__(256) void split_hs_kernel(const float* __restrict__ hs,
                                                       ushort_t* __restrict__ hh,
                                                       ushort_t* __restrict__ hl) {
  const int C8 = KPAD / 8;  // 132
  int idx = blockIdx.x * 256 + threadIdx.x;
  if (idx >= M_TOK * C8) return;
  int row = idx / C8, col = (idx % C8) * 8;
  pack8 ph, pl;
  if (col < DMODEL) {
    const float* p = &hs[(size_t)row * DMODEL + col];
#pragma unroll
    for (int j = 0; j < 8; ++j) splitf16(p[j], ph.u[j], pl.u[j]);
  } else {
#pragma unroll
    for (int j = 0; j < 8; ++j) { ph.u[j] = 0; pl.u[j] = 0; }
  }
  size_t o = (size_t)row * KPAD + col;
  *reinterpret_cast<uint4*>(&hh[o]) = ph.v;
  *reinterpret_cast<uint4*>(&hl[o]) = pl.v;
}

// ------- Wq||Wk transpose+split (fp16 scaled): Wt[n<1024][k<1056] ---------------------
__global__ __launch_bounds__(256) void split_wqk_kernel(const float* __restrict__ Wq,
                                                        const float* __restrict__ Wk,
                                                        ushort_t* __restrict__ th,
                                                        ushort_t* __restrict__ tl) {
  const int C8 = KPAD / 8;
  int idx = blockIdx.x * 256 + threadIdx.x;
  if (idx >= 1024 * C8) return;
  int n = idx / C8, k = (idx % C8) * 8;
  pack8 ph, pl;
#pragma unroll
  for (int j = 0; j < 8; ++j) {
    int kk = k + j;
    float val = 0.f;
    if (kk < DMODEL) val = (n < 512) ? Wq[(size_t)kk * 512 + n] : Wk[(size_t)kk * 512 + (n - 512)];
    splitf16(val, ph.u[j], pl.u[j]);
  }
  size_t o = (size_t)n * KPAD + k;
  *reinterpret_cast<uint4*>(&th[o]) = ph.v;
  *reinterpret_cast<uint4*>(&tl[o]) = pl.v;
}

// ------- Wv transpose (fp16 hi only): Wt[n<1152][k<1056] ------------------------------
__global__ __launch_bounds__(256) void split_wv_kernel(const float* __restrict__ Wv,
                                                       ushort_t* __restrict__ th) {
  const int C8 = KPAD / 8;
  int idx = blockIdx.x * 256 + threadIdx.x;
  if (idx >= NPADW * C8) return;
  int n = idx / C8, k = (idx % C8) * 8;
  pack8 ph;
#pragma unroll
  for (int j = 0; j < 8; ++j) {
    int kk = k + j;
    float val = (n < DMODEL && kk < DMODEL) ? Wv[(size_t)kk * DMODEL + n] : 0.f;
    ph.u[j] = __builtin_bit_cast(ushort_t, (_Float16)val);
  }
  *reinterpret_cast<uint4*>(&th[(size_t)n * KPAD + k]) = ph.v;
}

// ------- Wo transpose (bf16 single plane) with attn k-mapping k' = h*72+e -------------
__global__ __launch_bounds__(256) void split_wo_kernel(const float* __restrict__ Wo,
                                                       ushort_t* __restrict__ th) {
  const int C8O = KO / 8;  // 144
  int idx = blockIdx.x * 256 + threadIdx.x;
  if (idx >= NPADW * C8O) return;
  int n = idx / C8O, k = (idx % C8O) * 8;
  pack8 ph;
#pragma unroll
  for (int j = 0; j < 8; ++j) {
    int kk = k + j;           // attn feature index = h*72 + e
    int h = kk / 72, e = kk % 72;
    float val = (n < DMODEL && e < 65) ? Wo[(size_t)(h * 65 + e) * DMODEL + n] : 0.f;
    ph.u[j] = __builtin_bit_cast(ushort_t, __float2bfloat16(val));
  }
  *reinterpret_cast<uint4*>(&th[(size_t)n * KO + k]) = ph.v;
}

// ------- QK GEMM: fp16 2-plane 3-product, 512 threads (8 waves), dbuf issue-early -----
__global__ __launch_bounds__(512, 4) void gemm_qk(const ushort_t* __restrict__ Ahg,
                                                  const ushort_t* __restrict__ Alg,
                                                  const ushort_t* __restrict__ Bhg,
                                                  const ushort_t* __restrict__ Blg,
                                                  float* __restrict__ C, int kdim) {
  __shared__ ushort_t Ah[2][4096], Al[2][4096], Bh[2][4096], Bl[2][4096];
  const int t = threadIdx.x;         // 0..511
  const int w = t >> 6, l = t & 63;  // 8 waves
  int m0, n0;
  tile_map(blockIdx.x, 8, 16, m0, n0);
  const int wm = w >> 2, wn = w & 3;  // 2 x 4
  const int row16 = l & 15, g = l >> 4;

  f32x4 acc[4][2], acc2[4][2];
#pragma unroll
  for (int m = 0; m < 4; ++m)
#pragma unroll
    for (int n = 0; n < 2; ++n) { acc[m][n] = (f32x4){0,0,0,0}; acc2[m][n] = (f32x4){0,0,0,0}; }

  const int chunk = t;               // one 8-u16 chunk per plane per thread
  const int r0 = chunk >> 2;         // 0..127
  const int ch0 = (chunk & 3) ^ ((r0 ^ (r0 >> 2)) & 3);

#define STAGE_QK(K0, BUF)                                                       \
  {                                                                             \
    const size_t ga = (size_t)(m0 + r0) * kdim + (K0) + ch0 * 8;                \
    const size_t gb = (size_t)(n0 + r0) * kdim + (K0) + ch0 * 8;                \
    gload_lds16(Ahg + ga, &Ah[BUF][chunk * 8]);                                 \
    gload_lds16(Alg + ga, &Al[BUF][chunk * 8]);                                 \
    gload_lds16(Bhg + gb, &Bh[BUF][chunk * 8]);                                 \
    gload_lds16(Blg + gb, &Bl[BUF][chunk * 8]);                                 \
  }

  STAGE_QK(0, 0);
  __syncthreads();
  for (int k0 = 0, it = 0; k0 < kdim; k0 += 32, ++it) {
    const int cur = it & 1;
    if (k0 + 32 < kdim) STAGE_QK(k0 + 32, cur ^ 1);
    f16x8 fah[4], fal[4], fbh[2], fbl[2];
#pragma unroll
    for (int f = 0; f < 4; ++f) {
      const int ra = wm * 64 + f * 16 + row16;
      const int ca = (g ^ ((ra ^ (ra >> 2)) & 3)) << 3;
      fah[f] = *(const f16x8*)&Ah[cur][ra * 32 + ca];
      fal[f] = *(const f16x8*)&Al[cur][ra * 32 + ca];
    }
#pragma unroll
    for (int f = 0; f < 2; ++f) {
      const int rb = wn * 32 + f * 16 + row16;
      const int cb = (g ^ ((rb ^ (rb >> 2)) & 3)) << 3;
      fbh[f] = *(const f16x8*)&Bh[cur][rb * 32 + cb];
      fbl[f] = *(const f16x8*)&Bl[cur][rb * 32 + cb];
    }
#pragma unroll
    for (int m = 0; m < 4; ++m)
#pragma unroll
      for (int n = 0; n < 2; ++n) {
        acc[m][n]  = __builtin_amdgcn_mfma_f32_16x16x32_f16(fah[m], fbh[n], acc[m][n], 0, 0, 0);
        acc2[m][n] = __builtin_amdgcn_mfma_f32_16x16x32_f16(fah[m], fbl[n], acc2[m][n], 0, 0, 0);
        acc2[m][n] = __builtin_amdgcn_mfma_f32_16x16x32_f16(fal[m], fbh[n], acc2[m][n], 0, 0, 0);
      }
    __syncthreads();
  }
#undef STAGE_QK

  const float S2 = 1.0f / 4096.0f;
#pragma unroll
  for (int m = 0; m < 4; ++m)
#pragma unroll
    for (int n = 0; n < 2; ++n) {
      const int col = n0 + wn * 32 + n * 16 + row16;
      const int rowb = m0 + wm * 64 + m * 16 + g * 4;
#pragma unroll
      for (int i = 0; i < 4; ++i)
        C[(size_t)(rowb + i) * 1024 + col] = acc[m][n][i] + acc2[m][n][i] * S2;
    }
}

// ------- V GEMM: fp16 hi 1-product, 512 threads (8 waves), fp16 output ----------------
__global__ __launch_bounds__(512, 4) void gemm_v(const ushort_t* __restrict__ Ahg,
                                                 const ushort_t* __restrict__ Bhg,
                                                 ushort_t* __restrict__ Cv, int kdim) {
  __shared__ ushort_t Ah[2][4096], Bh[2][4096];
  const int t = threadIdx.x;
  const int w = t >> 6, l = t & 63;
  int m0, n0;
  tile_map(blockIdx.x, 9, 16, m0, n0);
  const int wm = w >> 2, wn = w & 3;
  const int row16 = l & 15, g = l >> 4;

  f32x4 acc[4][2];
#pragma unroll
  for (int m = 0; m < 4; ++m)
#pragma unroll
    for (int n = 0; n < 2; ++n) acc[m][n] = (f32x4){0,0,0,0};

  const int chunk = t;
  const int r0 = chunk >> 2;
  const int ch0 = (chunk & 3) ^ ((r0 ^ (r0 >> 2)) & 3);

#define STAGE_V(K0, BUF)                                                        \
  {                                                                             \
    const size_t ga = (size_t)(m0 + r0) * kdim + (K0) + ch0 * 8;                \
    const size_t gb = (size_t)(n0 + r0) * kdim + (K0) + ch0 * 8;                \
    gload_lds16(Ahg + ga, &Ah[BUF][chunk * 8]);                                 \
    gload_lds16(Bhg + gb, &Bh[BUF][chunk * 8]);                                 \
  }

  STAGE_V(0, 0);
  __syncthreads();
  for (int k0 = 0, it = 0; k0 < kdim; k0 += 32, ++it) {
    const int cur = it & 1;
    if (k0 + 32 < kdim) STAGE_V(k0 + 32, cur ^ 1);
    f16x8 fah[4], fbh[2];
#pragma unroll
    for (int f = 0; f < 4; ++f) {
      const int ra = wm * 64 + f * 16 + row16;
      const int ca = (g ^ ((ra ^ (ra >> 2)) & 3)) << 3;
      fah[f] = *(const f16x8*)&Ah[cur][ra * 32 + ca];
    }
#pragma unroll
    for (int f = 0; f < 2; ++f) {
      const int rb = wn * 32 + f * 16 + row16;
      const int cb = (g ^ ((rb ^ (rb >> 2)) & 3)) << 3;
      fbh[f] = *(const f16x8*)&Bh[cur][rb * 32 + cb];
    }
#pragma unroll
    for (int m = 0; m < 4; ++m)
#pragma unroll
      for (int n = 0; n < 2; ++n)
        acc[m][n] = __builtin_amdgcn_mfma_f32_16x16x32_f16(fah[m], fbh[n], acc[m][n], 0, 0, 0);
    __syncthreads();
  }
#undef STAGE_V

#pragma unroll
  for (int m = 0; m < 4; ++m)
#pragma unroll
    for (int n = 0; n < 2; ++n) {
      const int col = n0 + wn * 32 + n * 16 + row16;
      const int rowb = m0 + wm * 64 + m * 16 + g * 4;
#pragma unroll
      for (int i = 0; i < 4; ++i)
        Cv[(size_t)(rowb + i) * 1152 + col] =
            __builtin_bit_cast(ushort_t, (_Float16)acc[m][n][i]);
    }
}

// ------- O GEMM: single-plane bf16, 512 threads (8 waves) -----------------------------
__global__ __launch_bounds__(512, 4) void gemm_o(const ushort_t* __restrict__ Ahg,
                                                 const ushort_t* __restrict__ Bhg,
                                                 float* __restrict__ C, int kdim) {
  __shared__ ushort_t Ah[2][4096], Bh[2][4096];
  const int t = threadIdx.x;
  const int w = t >> 6, l = t & 63;
  int m0, n0;
  tile_map(blockIdx.x, 9, 16, m0, n0);
  const int wm = w >> 2, wn = w & 3;
  const int row16 = l & 15, g = l >> 4;

  f32x4 acc[4][2];
#pragma unroll
  for (int m = 0; m < 4; ++m)
#pragma unroll
    for (int n = 0; n < 2; ++n) acc[m][n] = (f32x4){0,0,0,0};

  const int chunk = t;
  const int r0 = chunk >> 2;
  const int ch0 = (chunk & 3) ^ ((r0 ^ (r0 >> 2)) & 3);

#define STAGE_O(K0, BUF)                                                        \
  {                                                                             \
    const size_t ga = (size_t)(m0 + r0) * kdim + (K0) + ch0 * 8;                \
    const size_t gb = (size_t)(n0 + r0) * kdim + (K0) + ch0 * 8;                \
    gload_lds16(Ahg + ga, &Ah[BUF][chunk * 8]);                                 \
    gload_lds16(Bhg + gb, &Bh[BUF][chunk * 8]);                                 \
  }

  STAGE_O(0, 0);
  __syncthreads();
  for (int k0 = 0, it = 0; k0 < kdim; k0 += 32, ++it) {
    const int cur = it & 1;
    if (k0 + 32 < kdim) STAGE_O(k0 + 32, cur ^ 1);
    bf16x8 fah[4], fbh[2];
#pragma unroll
    for (int f = 0; f < 4; ++f) {
      const int ra = wm * 64 + f * 16 + row16;
      const int ca = (g ^ ((ra ^ (ra >> 2)) & 3)) << 3;
      fah[f] = *(const bf16x8*)&Ah[cur][ra * 32 + ca];
    }
#pragma unroll
    for (int f = 0; f < 2; ++f) {
      const int rb = wn * 32 + f * 16 + row16;
      const int cb = (g ^ ((rb ^ (rb >> 2)) & 3)) << 3;
      fbh[f] = *(const bf16x8*)&Bh[cur][rb * 32 + cb];
    }
#pragma unroll
    for (int m = 0; m < 4; ++m)
#pragma unroll
      for (int n = 0; n < 2; ++n)
        acc[m][n] = __builtin_amdgcn_mfma_f32_16x16x32_bf16(fah[m], fbh[n], acc[m][n], 0, 0, 0);
    __syncthreads();
  }
#undef STAGE_O

#pragma unroll
  for (int m = 0; m < 4; ++m)
#pragma unroll
    for (int n = 0; n < 2; ++n) {
      const int col = n0 + wn * 32 + n * 16 + row16;
      if (col < DMODEL) {
        const int rowb = m0 + wm * 64 + m * 16 + g * 4;
#pragma unroll
        for (int i = 0; i < 4; ++i) C[(size_t)(rowb + i) * DMODEL + col] = acc[m][n][i];
      }
    }
}

// ---------------- kv state partials: phi(k)^T @ v per (bh, split) ---------------------
// 64 bh x 16 splits = 1024 blocks (4/CU at 34.8KB LDS), 4 chunks of 64 rows each.
// NO min-wave clamp (round-11 lesson: (256,8) forced VGPR=32 -> acc spill -> 1.6 GB).
__global__ __launch_bounds__(256) void kv_kernel(const float* __restrict__ qk,
                                                 const ushort_t* __restrict__ vbuf,
                                                 float* __restrict__ kvpart,
                                                 float* __restrict__ kspart) {
  const int bh = blockIdx.x;    // 0..63
  const int split = blockIdx.y; // 0..KVSPLIT-1
  const int b = bh >> 4, h = bh & 15;
  __shared__ float ks[64][68];
  __shared__ float vs[64][68];
  const int tid = threadIdx.x;
  const int t1 = 256 + tid;
  const int d00 = (tid / 17) * 4, e00 = (tid % 17) * 4;
  const int d10 = (t1 / 17) * 4, e10 = (t1 % 17) * 4;
  float acc0[16] = {};
  float acc1[16] = {};
  float kcol = 0.f;

  for (int chunk = 0; chunk < 4; ++chunk) {
    const int nb = split * 256 + chunk * 64;
    for (int idx = tid; idx < 64 * 65; idx += 256) {
      const int r = idx / 65, d = idx % 65;
      const size_t row = (size_t)(b * S_LEN + nb + r);
      float val;
      if (d == 0) val = 1.f;
      else if (d <= 32) val = qk[row * 1024 + 512 + h * 32 + (d - 1)];
      else {
        float x = qk[row * 1024 + 512 + h * 32 + (d - 33)];
        val = 0.5f * x * x;
      }
      ks[r][d] = val;
      vs[r][d] = (float)__builtin_bit_cast(_Float16, vbuf[row * 1152 + h * 65 + d]);
    }
    __syncthreads();
    for (int r = 0; r < 64; ++r) {
      float a[4], v[4];
#pragma unroll
      for (int i = 0; i < 4; ++i) a[i] = ks[r][d00 + i];
#pragma unroll
      for (int j = 0; j < 4; ++j) v[j] = vs[r][e00 + j];
#pragma unroll
      for (int i = 0; i < 4; ++i)
#pragma unroll
        for (int j = 0; j < 4; ++j) acc0[i * 4 + j] += a[i] * v[j];
    }
    if (tid < 33) {
      for (int r = 0; r < 64; ++r) {
        float a[4], v[4];
#pragma unroll
        for (int i = 0; i < 4; ++i) a[i] = ks[r][d10 + i];
#pragma unroll
        for (int j = 0; j < 4; ++j) v[j] = vs[r][e10 + j];
#pragma unroll
        for (int i = 0; i < 4; ++i)
#pragma unroll
          for (int j = 0; j < 4; ++j) acc1[i * 4 + j] += a[i] * v[j];
      }
    }
    if (tid < 65) {
      float s = 0.f;
      for (int r = 0; r < 64; ++r) s += ks[r][tid];
      kcol += s;
    }
    __syncthreads();
  }

  float* kvp = kvpart + ((size_t)split * 64 + bh) * 4225;
#pragma unroll
  for (int i = 0; i < 4; ++i)
#pragma unroll
    for (int j = 0; j < 4; ++j) {
      int d = d00 + i, e = e00 + j;
      if (d < 65 && e < 65) kvp[d * 65 + e] = acc0[i * 4 + j];
    }
  if (tid < 33) {
#pragma unroll
    for (int i = 0; i < 4; ++i)
#pragma unroll
      for (int j = 0; j < 4; ++j) {
        int d = d10 + i, e = e10 + j;
        if (d < 65 && e < 65) kvp[d * 65 + e] = acc1[i * 4 + j];
      }
  }
  if (tid < 65) kspart[((size_t)split * 64 + bh) * 65 + tid] = kcol;
}

__global__ __launch_bounds__(256) void kv_reduce(const float* __restrict__ kvpart,
                                                 const float* __restrict__ kspart,
                                                 float* __restrict__ kv,
                                                 float* __restrict__ ksum) {
  const int NKV = 64 * 4225;
  const int NKS = 64 * 65;
  int i = blockIdx.x * 256 + threadIdx.x;
  if (i < NKV) {
    float s = 0.f;
#pragma unroll 8
    for (int p = 0; p < KVSPLIT; ++p) s += kvpart[(size_t)p * NKV + i];
    kv[i] = s;
  } else if (i < NKV + NKS) {
    int j = i - NKV;
    float s = 0.f;
#pragma unroll 8
    for (int p = 0; p < KVSPLIT; ++p) s += kspart[p * NKS + j];
    ksum[j] = s;
  }
}

// ------- phi(q)@kv, normalize, mask; write attn bf16 (single plane), k' = h*72+e ------
__global__ __launch_bounds__(256, 6) void qkv_kernel(const float* __restrict__ qk,
                                                     const float* __restrict__ kv,
                                                     const float* __restrict__ ksum,
                                                     const int* __restrict__ mask,
                                                     uint_t* __restrict__ ath32) {
  const int gx = blockIdx.x;   // 0..127 (32-token chunks within batch)
  const int bh = blockIdx.y;   // 0..63
  const int b = bh >> 4, h = bh & 15;
  __shared__ float kvs[65 * 68];
  __shared__ float phis[32][68];
  __shared__ float kss[65];
  __shared__ float qsums[32];
  const int tid = threadIdx.x;

  const float* kvp = kv + (size_t)bh * 4225;
  for (int i = tid; i < 4225; i += 256) kvs[(i / 65) * 68 + (i % 65)] = kvp[i];
  for (int idx = tid; idx < 1024; idx += 256) {
    int tt = idx >> 5, f = idx & 31;
    size_t row = (size_t)(b * S_LEN + gx * 32 + tt);
    float val = qk[row * 1024 + h * 32 + f];
    phis[tt][1 + f] = val;
    phis[tt][33 + f] = 0.5f * val * val;
  }
  if (tid < 32) phis[tid][0] = 1.f;
  if (tid < 65) kss[tid] = ksum[bh * 65 + tid];
  __syncthreads();
  if (tid < 32) {
    float s = 0.f;
    for (int d = 0; d < 65; ++d) s += phis[tid][d];
    qsums[tid] = s;
  }
  __syncthreads();

  const int tt = tid >> 3, fg = tid & 7;
  float accs[8] = {0.f, 0.f, 0.f, 0.f, 0.f, 0.f, 0.f, 0.f};
  const float* ph = phis[tt];
#pragma unroll 4
  for (int d = 0; d < 65; ++d) {
    float p = ph[d];
    const float* kr = &kvs[d * 68 + fg * 8];
    float4 va = *reinterpret_cast<const float4*>(kr);
    float4 vb = *reinterpret_cast<const float4*>(kr + 4);
    accs[0] += p * va.x; accs[1] += p * va.y; accs[2] += p * va.z; accs[3] += p * va.w;
    accs[4] += p * vb.x; accs[5] += p * vb.y; accs[6] += p * vb.z; accs[7] += p * vb.w;
  }
  float a64 = 0.f;
  if (fg == 0) {
#pragma unroll 4
    for (int d = 0; d < 65; ++d) a64 += ph[d] * kvs[d * 68 + 64];
  }

  const int s_in_b = gx * 32 + tt;
  const size_t row = (size_t)(b * S_LEN + s_in_b);
  const int m = mask[b * S_LEN + s_in_b];
  const float qs = qsums[tt];
  const float fm = (m == 0) ? 0.f : 1.f;
  float o[8];
#pragma unroll
  for (int j = 0; j < 8; ++j) {
    float z = qs * kss[fg * 8 + j] + 1e-9f;
    o[j] = fm * accs[j] / z;
  }
  const size_t base = row * 576 + h * 36 + fg * 4;  // u32 units; row = 1152 u16
  pack8 phh;
#pragma unroll
  for (int j = 0; j < 8; ++j)
    phh.u[j] = __builtin_bit_cast(ushort_t, __float2bfloat16(o[j]));
  *reinterpret_cast<uint4*>(&ath32[base]) = phh.v;
  if (fg == 0) {
    float z = qs * kss[64] + 1e-9f;
    float o64 = fm * a64 / z;
    uint4 tailh = {(uint_t)__builtin_bit_cast(ushort_t, __float2bfloat16(o64)), 0u, 0u, 0u};
    *reinterpret_cast<uint4*>(&ath32[row * 576 + h * 36 + 32]) = tailh;
  }
}

extern "C" void kernel_launch(void* const* d_in, const int* in_sizes, int n_in,
                              void* d_out, int out_size, void* d_ws, size_t ws_size,
                              hipStream_t stream) {
  const float* hs = (const float*)d_in[0];
  const int* mask = (const int*)d_in[1];
  const float* Wq = (const float*)d_in[2];
  const float* Wk = (const float*)d_in[3];
  const float* Wv = (const float*)d_in[4];
  const float* Wo = (const float*)d_in[5];
  float* out = (float*)d_out;

  // Liveness-aliased full-M layout (148.9 MB total, < 167 MB proven in round 2):
  //   R_A (34.6 MB): hsh (split_hs..gemm_v) -> kv+ksum+kvpart+kspart (kv_kernel..qkv)
  //   R_B (37.75 MB): hsl (..gemm_qk) -> vbuf (gemm_v..kv_kernel) -> attn (qkv..gemm_o)
  //   R_C (67.1 MB): qkbuf (gemm_qk..qkv)
  //   R_W (9.4 MB): weight planes
  // Stream ordering serializes kernels, making each alias transition safe.
  const size_t RA_BYTES = (size_t)M_TOK * KPAD * 2;        // 34.6 MB
  const size_t RB_BYTES = (size_t)M_TOK * 1152 * 2;        // 37.75 MB

  char* base = (char*)d_ws;
  ushort_t* hsh = (ushort_t*)base;                         // R_A as hsh
  float* kv = (float*)base;                                // R_A as kv state
  float* ksum = kv + 64 * 4225;
  float* kvpart = ksum + 64 * 65;
  float* kspart = kvpart + (size_t)KVSPLIT * 64 * 4225;
  char* rb = base + RA_BYTES;
  ushort_t* hsl = (ushort_t*)rb;                           // R_B as hsl
  ushort_t* vbuf = (ushort_t*)rb;                          // R_B as v (fp16)
  uint_t* ath32 = (uint_t*)rb;                             // R_B as attn (bf16)
  char* rc = rb + RB_BYTES;
  float* qkbuf = (float*)rc;                               // R_C
  char* rw = rc + (size_t)M_TOK * 1024 * 4;
  ushort_t* Wqkh = (ushort_t*)rw;                          // [1024][1056] fp16 hi
  ushort_t* Wqkl = Wqkh + (size_t)1024 * KPAD;             // lo
  ushort_t* Wvh = Wqkl + (size_t)1024 * KPAD;              // [1152][1056] fp16 hi
  ushort_t* Woh = Wvh + (size_t)NPADW * KPAD;              // [1152][1152] bf16

  dim3 blk(256);
  const int C8 = KPAD / 8;
  const int C8O = KO / 8;

  split_wqk_kernel<<<(1024 * C8 + 255) / 256, blk, 0, stream>>>(Wq, Wk, Wqkh, Wqkl);
  split_wv_kernel<<<(NPADW * C8 + 255) / 256, blk, 0, stream>>>(Wv, Wvh);
  split_wo_kernel<<<(NPADW * C8O + 255) / 256, blk, 0, stream>>>(Wo, Woh);

  split_hs_kernel<<<(M_TOK * C8 + 255) / 256, blk, 0, stream>>>(hs, hsh, hsl);

  // q|k projection: fp32-grade 3-product fp16; 1024 blocks x 512 threads
  gemm_qk<<<1024, dim3(512), 0, stream>>>(hsh, hsl, Wqkh, Wqkl, qkbuf, KPAD);
  // v projection: 1-product fp16, fp16 output (overwrites hsl — dead after gemm_qk)
  gemm_v<<<1152, dim3(512), 0, stream>>>(hsh, Wvh, vbuf, KPAD);

  // kv state (writes into R_A — hsh dead after gemm_v)
  kv_kernel<<<dim3(64, KVSPLIT), blk, 0, stream>>>(qkbuf, vbuf, kvpart, kspart);
  kv_reduce<<<(64 * 4225 + 64 * 65 + 255) / 256, blk, 0, stream>>>(kvpart, kspart, kv, ksum);

  // attn (overwrites vbuf — dead after kv_kernel)
  qkv_kernel<<<dim3(128, 64), blk, 0, stream>>>(qkbuf, kv, ksum, mask, ath32);

  gemm_o<<<1152, dim3(512), 0, stream>>>((ushort_t*)ath32, Woh, out, KO);
}